// Round 11
// baseline (737.714 us; speedup 1.0000x reference)
//
#include <hip/hip_runtime.h>
#include <hip/hip_bf16.h>

// QuantizedLinear: out[m,o] = sum_k x[m,k] * (q[o,k]-z[o,g])*s[o,g] + b[o]
// M=8192, K=4096, N=11008. Pass1: dequant W->bf16 (row-major B^T), cvt x->bf16.
// Pass2: 256x256 bf16 GEMM (R10 structure: 2 phases/K-tile, read|BAR|MFMA
// handshake, counted vmcnt(4), T1 XCD swizzle, T2 LDS swizzle, T5 setprio).
// NEW (R11): tail-split-K. 1376 tiles = 5.375 rounds of 256 CUs; the last 96
// tiles are split into two half-K jobs each: grid = 1280 full + 192 half jobs
// (fulls dispatched first, LPT). A pre-kernel zeroes the 96 tail tiles' C;
// half jobs atomicAdd(acc + bias/2). Deterministic: 0+x+y, fp32 a+b==b+a
// bit-exact, bias*0.5 exact. Makespan ~6T -> ~5.5T.

#define K_DIM 4096
#define N_DIM 11008
#define M_DIM 8192
#define NGRP 32

typedef __bf16 bf16x8 __attribute__((ext_vector_type(8)));
typedef float f32x4 __attribute__((ext_vector_type(4)));
typedef unsigned short u16x8 __attribute__((ext_vector_type(8)));

__device__ __forceinline__ unsigned short f2bf(float f) {
  unsigned u = __builtin_bit_cast(unsigned, f);
  return (unsigned short)((u + 0x7FFFu + ((u >> 16) & 1u)) >> 16);  // RNE
}

__device__ __forceinline__ void gload_lds16(const void* g, void* l) {
  __builtin_amdgcn_global_load_lds(
      (const __attribute__((address_space(1))) unsigned int*)(unsigned long long)g,
      (__attribute__((address_space(3))) unsigned int*)(unsigned int)(unsigned long long)l,
      16, 0, 0);
}

// ---- pass 1a: x fp32 -> bf16 ----
__global__ __launch_bounds__(256) void cvt_x_kernel(const float4* __restrict__ x4,
                                                    u16x8* __restrict__ xb) {
  int i = blockIdx.x * 256 + threadIdx.x;
  float4 a = x4[2 * i], b = x4[2 * i + 1];
  u16x8 r;
  r[0] = f2bf(a.x); r[1] = f2bf(a.y); r[2] = f2bf(a.z); r[3] = f2bf(a.w);
  r[4] = f2bf(b.x); r[5] = f2bf(b.y); r[6] = f2bf(b.z); r[7] = f2bf(b.w);
  xb[i] = r;
}

// ---- pass 1b: dequant W -> bf16 (row-major [N][K]) ----
__global__ __launch_bounds__(256) void dequant_kernel(const int4* __restrict__ q4,
                                                      const float* __restrict__ scales,
                                                      const float* __restrict__ zeros,
                                                      u16x8* __restrict__ wb) {
  int t = blockIdx.x * 256 + threadIdx.x;
  int o = t >> 9;
  int j8 = t & 511;
  int g = j8 >> 4;
  float s = scales[o * NGRP + g];
  float z = zeros[o * NGRP + g];
  float nzs = -z * s;
  int4 qa = q4[2 * t], qb = q4[2 * t + 1];
  u16x8 r;
  r[0] = f2bf(fmaf((float)qa.x, s, nzs));
  r[1] = f2bf(fmaf((float)qa.y, s, nzs));
  r[2] = f2bf(fmaf((float)qa.z, s, nzs));
  r[3] = f2bf(fmaf((float)qa.w, s, nzs));
  r[4] = f2bf(fmaf((float)qb.x, s, nzs));
  r[5] = f2bf(fmaf((float)qb.y, s, nzs));
  r[6] = f2bf(fmaf((float)qb.z, s, nzs));
  r[7] = f2bf(fmaf((float)qb.w, s, nzs));
  wb[t] = r;
}

// ---- zero the 96 tail tiles' C regions (before gemm; stream-ordered) ----
__global__ __launch_bounds__(256) void ztail_kernel(float* __restrict__ C) {
  int i = blockIdx.x * 256 + threadIdx.x;   // 96 * 65536 threads
  int r = i >> 16;                          // tail tile 0..95
  int w = i & 65535;
  int tile = 1280 + r;
  int swz = (tile & 7) * 172 + (tile >> 3);
  int tm = swz / 43, tn = swz % 43;
  int row = w >> 8, col = w & 255;
  C[(size_t)(tm * 256 + row) * N_DIM + (tn * 256 + col)] = 0.f;
}

// ---- pass 2: 256x256 bf16 GEMM, 2 phases / K-tile, read|BAR|MFMA handshake ----
#define BAR() __builtin_amdgcn_s_barrier()
#define SCHED0() __builtin_amdgcn_sched_barrier(0)

__global__ __launch_bounds__(512, 2) void gemm_kernel(const unsigned short* __restrict__ A,
                                                      const unsigned short* __restrict__ B,
                                                      const float* __restrict__ bias,
                                                      float* __restrict__ C) {
  extern __shared__ unsigned short smem[];
  unsigned short* sAb = smem;           // [2 buf][2 half][8192]
  unsigned short* sBb = smem + 32768;

  // Job decode: j<1280 full-K tile j; else half-K of tail tile 1280+(r%96),
  // k-half (r/96). All block-uniform.
  const int j = blockIdx.x;
  int tileIdx, k0i, nhalf;  // nhalf = nk/2 pairs
  bool isFull;
  if (j < 1280) {
    tileIdx = j; k0i = 0; nhalf = 32; isFull = true;
  } else {
    int r = j - 1280;
    tileIdx = 1280 + (r % 96);
    k0i = (r / 96) * 32;
    nhalf = 16; isFull = false;
  }
  const int lim = nhalf - 1;

  // T1: 1376-tile space, %8==0 -> simple bijective XCD swizzle.
  const int swz = (tileIdx & 7) * 172 + (tileIdx >> 3);
  const int tm = swz / 43, tn = swz % 43;

  const int tid = threadIdx.x;
  const int w = tid >> 6, l = tid & 63;
  const int wr = w >> 2, wc = w & 3;

  const int dsto = w * 512 + l * 8;            // LDS elem offset (wave base + lane*16B)
  const int gs = (l & 7) ^ (l >> 3);           // inverse T2 swizzle on global source slot
  const unsigned short* gA = A + (size_t)(tm * 256 + (tid >> 3)) * K_DIM + gs * 8;
  const unsigned short* gB = B + (size_t)(tn * 256 + (tid >> 3)) * K_DIM + gs * 8;

#define STG_A(tt, h, dst)                                                       \
  do {                                                                          \
    const unsigned short* _s = gA + (size_t)(h) * 128 * K_DIM + (tt) * 64;      \
    gload_lds16(_s, (dst) + dsto);                                              \
    gload_lds16(_s + 64 * K_DIM, (dst) + 4096 + dsto);                          \
  } while (0)
#define STG_B(tt, h, dst)                                                       \
  do {                                                                          \
    const unsigned short* _s = gB + (size_t)(h) * 128 * K_DIM + (tt) * 64;      \
    gload_lds16(_s, (dst) + dsto);                                              \
    gload_lds16(_s + 64 * K_DIM, (dst) + 4096 + dsto);                          \
  } while (0)

  // fragment read coords (16x16x32: lane row=l&15, k-chunk=l>>4, swizzled slots)
  const int fr = l & 15, sb = l >> 4, x7 = l & 7;
  const int abase = (wr * 64 + fr) * 64;
  const int bbase = (wc * 32 + fr) * 64;
  const int k0 = (sb ^ x7) * 8;
  const int k1 = ((sb + 4) ^ x7) * 8;

  bf16x8 av[4][2], bva[2][2], bvb[2][2];
  f32x4 acc[8][4] = {};

#define READ_A(half)                                                     \
  {                                                                      \
    _Pragma("unroll") for (int m = 0; m < 4; ++m) {                      \
      av[m][0] = *(const bf16x8*)((half) + abase + m * 1024 + k0);       \
      av[m][1] = *(const bf16x8*)((half) + abase + m * 1024 + k1);       \
    }                                                                    \
  }
#define READ_B(half, arr)                                                \
  {                                                                      \
    _Pragma("unroll") for (int n = 0; n < 2; ++n) {                      \
      arr[n][0] = *(const bf16x8*)((half) + bbase + n * 1024 + k0);      \
      arr[n][1] = *(const bf16x8*)((half) + bbase + n * 1024 + k1);      \
    }                                                                    \
  }
#define MFMA_Q(mh, nh, arr)                                                        \
  {                                                                                \
    __builtin_amdgcn_s_setprio(1);                                                 \
    _Pragma("unroll") for (int kk = 0; kk < 2; ++kk)                               \
    _Pragma("unroll") for (int m = 0; m < 4; ++m)                                  \
    _Pragma("unroll") for (int nn = 0; nn < 2; ++nn)                               \
      acc[(mh)*4 + m][(nh)*2 + nn] = __builtin_amdgcn_mfma_f32_16x16x32_bf16(      \
          av[m][kk], arr[nn][kk], acc[(mh)*4 + m][(nh)*2 + nn], 0, 0, 0);          \
    __builtin_amdgcn_s_setprio(0);                                                 \
  }

  // ---- prologue: tile k0i all 4 halves + (k0i+1) A0, B1 into buf1 ----
  STG_A(k0i, 0, sAb);
  STG_A(k0i, 1, sAb + 8192);
  STG_B(k0i, 0, sBb);
  STG_B(k0i, 1, sBb + 8192);
  STG_A(k0i + 1, 0, sAb + 16384);
  STG_B(k0i + 1, 1, sBb + 16384 + 8192);
  asm volatile("s_waitcnt vmcnt(4)" ::: "memory");
  BAR();
  SCHED0();

  for (int tt = 0; tt < nhalf; ++tt) {
    const int te = k0i + 2 * tt;  // even global K-tile

    // ======== even tile (cur = buf0, nxt = buf1) ========
    READ_A(sAb);
    READ_B(sBb, bva);
    READ_B(sBb + 8192, bvb);
    STG_A(te + 1, 1, sAb + 16384 + 8192);
    STG_B(te + 1, 0, sBb + 16384);
    SCHED0();
    BAR();
    SCHED0();
    MFMA_Q(0, 0, bva);
    MFMA_Q(0, 1, bvb);
    // P2
    READ_A(sAb + 8192);
    if (tt < lim) {
      STG_A(te + 2, 0, sAb);
      STG_B(te + 2, 1, sBb + 8192);
    }
    if (tt < lim) {
      asm volatile("s_waitcnt vmcnt(4)" ::: "memory");
    } else {
      asm volatile("s_waitcnt vmcnt(0)" ::: "memory");
    }
    SCHED0();
    BAR();
    SCHED0();
    MFMA_Q(1, 1, bvb);
    MFMA_Q(1, 0, bva);

    // ======== odd tile (cur = buf1, nxt = buf0) ========
    READ_A(sAb + 16384);
    READ_B(sBb + 16384, bva);
    READ_B(sBb + 16384 + 8192, bvb);
    if (tt < lim) {
      STG_A(te + 2, 1, sAb + 8192);
      STG_B(te + 2, 0, sBb);
    }
    SCHED0();
    BAR();
    SCHED0();
    MFMA_Q(0, 0, bva);
    MFMA_Q(0, 1, bvb);
    // P2
    READ_A(sAb + 16384 + 8192);
    if (tt < lim) {
      STG_A(te + 3, 0, sAb + 16384);
      STG_B(te + 3, 1, sBb + 16384 + 8192);
    }
    if (tt < lim) {
      asm volatile("s_waitcnt vmcnt(4)" ::: "memory");
      SCHED0();
      BAR();
      SCHED0();
    }
    MFMA_Q(1, 1, bvb);
    MFMA_Q(1, 0, bva);
  }

  // ---- epilogue: C/D layout col=lane&15, row=(lane>>4)*4+reg ----
  const int r0 = tm * 256 + wr * 64 + sb * 4;
  const int c0 = tn * 256 + wc * 32 + fr;
  const float bsc = isFull ? 1.0f : 0.5f;
#pragma unroll
  for (int n = 0; n < 4; ++n) {
    const int col = c0 + (n >> 1) * 128 + (n & 1) * 16;
    const float bv = bias[col] * bsc;
#pragma unroll
    for (int mi = 0; mi < 8; ++mi) {
      const int row = r0 + (mi >> 2) * 128 + (mi & 3) * 16;
      if (isFull) {
#pragma unroll
        for (int jj = 0; jj < 4; ++jj)
          C[(size_t)(row + jj) * N_DIM + col] = acc[mi][n][jj] + bv;
      } else {
#pragma unroll
        for (int jj = 0; jj < 4; ++jj)
          atomicAdd(&C[(size_t)(row + jj) * N_DIM + col], acc[mi][n][jj] + bv);
      }
    }
  }
}

extern "C" void kernel_launch(void* const* d_in, const int* in_sizes, int n_in,
                              void* d_out, int out_size, void* d_ws, size_t ws_size,
                              hipStream_t stream) {
  const float* x = (const float*)d_in[0];
  const int* qw = (const int*)d_in[1];
  const float* sc = (const float*)d_in[2];
  const float* zr = (const float*)d_in[3];
  const float* bs = (const float*)d_in[4];
  float* out = (float*)d_out;

  const size_t xb_bytes = (size_t)M_DIM * K_DIM * 2;
  const size_t wb_bytes = (size_t)N_DIM * K_DIM * 2;
  if (ws_size < xb_bytes + wb_bytes) return;

  unsigned short* xb = (unsigned short*)d_ws;
  unsigned short* wb = (unsigned short*)((char*)d_ws + xb_bytes);

  (void)hipFuncSetAttribute((const void*)gemm_kernel,
                            hipFuncAttributeMaxDynamicSharedMemorySize, 131072);

  cvt_x_kernel<<<(M_DIM * K_DIM / 8) / 256, 256, 0, stream>>>((const float4*)x, (u16x8*)xb);
  dequant_kernel<<<(N_DIM * K_DIM / 8) / 256, 256, 0, stream>>>((const int4*)qw, sc, zr,
                                                                (u16x8*)wb);
  ztail_kernel<<<(96 * 65536) / 256, 256, 0, stream>>>(out);
  gemm_kernel<<<1280 + 192, 512, 131072, stream>>>(xb, wb, bs, out);
}